// Round 19
// baseline (85.859 us; speedup 1.0000x reference)
//
#include <hip/hip_runtime.h>
#include <hip/hip_bf16.h>

#define KD 960
#define BT 1536   // 16*96
#define NB 16

typedef __attribute__((ext_vector_type(8))) short bf16x8;
typedef __attribute__((ext_vector_type(4))) float f32x4;

#define MFMA_16x16x32_BF16 __builtin_amdgcn_mfma_f32_16x16x32_bf16

// pack 8 f32 -> 8 bf16 (16B) and store to LDS
__device__ __forceinline__ void pack8(float4 a, float4 b, void* dst) {
    union { short s[8]; bf16x8 v; } u;
#pragma unroll
    for (int i = 0; i < 4; i++) {
        __hip_bfloat16 h0 = __float2bfloat16(((const float*)&a)[i]);
        __hip_bfloat16 h1 = __float2bfloat16(((const float*)&b)[i]);
        u.s[i]     = *(short*)&h0;
        u.s[i + 4] = *(short*)&h1;
    }
    *(bf16x8*)dst = u.v;
}

__device__ __forceinline__ bf16x8 ldfrag(const char* lds, int row, int slot) {
    int ss = slot ^ (row & 7);
    return *(const bf16x8*)(lds + row * 128 + ss * 16);
}

// gload_lds staging: 64 rows x 64 bf16 (XOR-swizzled source), 4-wave form
__device__ __forceinline__ void stage64(const char* gRow0, int ldbytes,
                                        char* ldsTile, int wv, int lane) {
#pragma unroll
    for (int rd = 0; rd < 2; rd++) {
        int c  = rd * 256 + wv * 64 + lane;
        int r  = c >> 3;
        int sl = c & 7;
        int ss = sl ^ (r & 7);
        const char* g = gRow0 + (size_t)r * ldbytes + ss * 16;
        __builtin_amdgcn_global_load_lds((const void*)g,
            (void*)(ldsTile + rd * 4096 + wv * 1024), 16, 0, 0);
    }
}
// 32 rows x 64 bf16 (4KB), one 16B load per thread (256 thr)
__device__ __forceinline__ void stage32(const char* gRow0, int ldbytes,
                                        char* ldsTile, int tid, int wv) {
    int r  = tid >> 3;
    int sl = tid & 7;
    int ss = sl ^ (r & 7);
    const char* g = gRow0 + (size_t)r * ldbytes + ss * 16;
    __builtin_amdgcn_global_load_lds((const void*)g,
        (void*)(ldsTile + wv * 1024), 16, 0, 0);
}

// =============== embed MFMA (reg-staged concat/W_e) + elementwise prep ========
__global__ __launch_bounds__(256) void embedprep_kernel(
    const float* __restrict__ X, const float* __restrict__ M,
    const float* __restrict__ DF, const float* __restrict__ We,
    const float* __restrict__ Wa, const float* __restrict__ Va,
    const float* __restrict__ W_imp,
    const float* __restrict__ b_e, const float* __restrict__ pos,
    __hip_bfloat16* __restrict__ heb, __hip_bfloat16* __restrict__ heT,
    __hip_bfloat16* __restrict__ Wab, __hip_bfloat16* __restrict__ Vab,
    float* __restrict__ MT, float* __restrict__ DFT,
    float* __restrict__ Wdiag) {
    int bid = blockIdx.x;
    if (bid < 720) {
        __shared__ __align__(16) char lds[12288];
        char* As = lds; char* Bs = lds + 4096;
        int tid = threadIdx.x, lane = tid & 63, wv = tid >> 6;
        int lq = lane >> 4, lr = lane & 15;
        int m0 = (bid / 15) * 32, n0 = (bid % 15) * 64;
        int wm = (wv >> 1) * 16, wn = (wv & 1) * 32;
        int r8 = tid >> 3, sl = tid & 7;
        f32x4 acc[2] = {};
        for (int kt = 0; kt < 5; kt++) {
            int c = kt * 64 + sl * 8;
            {
                int m = m0 + r8;
                float4 f0 = {0.f,0.f,0.f,0.f}, f1 = {0.f,0.f,0.f,0.f};
                if (c < 96) {
                    const float* s = X + (size_t)m * 96 + c;
                    f0 = *(const float4*)s; f1 = *(const float4*)(s + 4);
                } else if (c < 192) {
                    const float* s = M + (size_t)m * 96 + (c - 96);
                    f0 = *(const float4*)s; f1 = *(const float4*)(s + 4);
                } else if (c < 288) {
                    const float* s = DF + (size_t)m * 96 + (c - 192);
                    f0 = *(const float4*)s; f1 = *(const float4*)(s + 4);
                }
                pack8(f0, f1, As + r8 * 128 + ((sl ^ (r8 & 7)) * 16));
            }
#pragma unroll
            for (int h = 0; h < 2; h++) {
                int row = h * 32 + r8;
                int n = n0 + row;
                float4 f0 = {0.f,0.f,0.f,0.f}, f1 = {0.f,0.f,0.f,0.f};
                if (c < 288) {
                    const float* s = We + (size_t)n * 288 + c;
                    f0 = *(const float4*)s; f1 = *(const float4*)(s + 4);
                }
                pack8(f0, f1, Bs + row * 128 + ((sl ^ (row & 7)) * 16));
            }
            __syncthreads();
#pragma unroll
            for (int h = 0; h < 2; h++) {
                bf16x8 a  = ldfrag(As, wm + lr, h * 4 + lq);
                bf16x8 b0 = ldfrag(Bs, wn + lr,      h * 4 + lq);
                bf16x8 b1 = ldfrag(Bs, wn + 16 + lr, h * 4 + lq);
                acc[0] = MFMA_16x16x32_BF16(a, b0, acc[0], 0, 0, 0);
                acc[1] = MFMA_16x16x32_BF16(a, b1, acc[1], 0, 0, 0);
            }
            __syncthreads();
        }
        int mbase = m0 + wm + lq * 4;
        int b = mbase / 96, t0 = mbase % 96;
#pragma unroll
        for (int ni = 0; ni < 2; ni++) {
            int n = n0 + wn + ni * 16 + lr;
            float bn = b_e[n];
            ushort4 pk;
#pragma unroll
            for (int reg = 0; reg < 4; reg++) {
                int t = t0 + reg;
                float x = acc[ni][reg] + bn + pos[t * KD + n];
                x = x > 0.f ? x : (__expf(x) - 1.f);
                __hip_bfloat16 hv = __float2bfloat16(x);
                heb[(size_t)(mbase + reg) * KD + n] = hv;
                ((unsigned short*)&pk)[reg] = *(unsigned short*)&hv;
            }
            *(ushort4*)((char*)heT + (((size_t)b * 960 + n) * 96 + t0) * 2) = pk;
        }
        return;
    }
    // elementwise prep
    int idx = (bid - 720) * 256 + threadIdx.x;
    if (idx < 921600) { Wab[idx] = __float2bfloat16(Wa[idx]); return; }
    idx -= 921600;
    if (idx < 921600) { Vab[idx] = __float2bfloat16(Va[idx]); return; }
    idx -= 921600;
    if (idx < 147456) {               // MT[b][d][t] = M[b][t][d]
        int b = idx / 9216, r = idx % 9216, d = r / 96, t = r % 96;
        MT[idx] = M[(b * 96 + t) * 96 + d];
        return;
    }
    idx -= 147456;
    if (idx < 147456) {
        int b = idx / 9216, r = idx % 9216, d = r / 96, t = r % 96;
        DFT[idx] = DF[(b * 96 + t) * 96 + d];
        return;
    }
    idx -= 147456;
    if (idx < 960) {                  // diagonal of W_imp, kd-major
        int k = idx / 96, d = idx % 96;
        Wdiag[idx] = W_imp[d * KD + k * 96 + d];
    }
}

// =============== fused key/qry GEMM 64x32; 3-buffer 2-deep pipeline ============
#define KQ_BUF 16384   // A 8KB + B1 4KB + B2 4KB
__global__ __launch_bounds__(256) void kq_mfma(
    const __hip_bfloat16* __restrict__ A, const __hip_bfloat16* __restrict__ B1,
    const __hip_bfloat16* __restrict__ B2,
    float* __restrict__ EK, float* __restrict__ EQ) {
    __shared__ __align__(16) char lds[3 * KQ_BUF];
    int tid = threadIdx.x, lane = tid & 63, wv = tid >> 6;
    int lq = lane >> 4, lr = lane & 15;
    int m0 = blockIdx.y * 64, n0 = blockIdx.x * 32;
    int wm = (wv >> 1) * 32, wn = (wv & 1) * 16;
    const char* Ab  = (const char*)A  + (size_t)m0 * 1920;
    const char* B1b = (const char*)B1 + (size_t)n0 * 1920;
    const char* B2b = (const char*)B2 + (size_t)n0 * 1920;
    f32x4 aK[2] = {}, aQ[2] = {};

#pragma unroll
    for (int p = 0; p < 2; p++) {
        char* buf = lds + p * KQ_BUF;
        int k0b = p * 128;
        stage64(Ab  + k0b, 1920, buf,         wv, lane);
        stage32(B1b + k0b, 1920, buf + 8192,  tid, wv);
        stage32(B2b + k0b, 1920, buf + 12288, tid, wv);
    }
    for (int kt = 0; kt < 15; kt++) {
        if (kt < 13) {
            char* nbuf = lds + ((kt + 2) % 3) * KQ_BUF;
            int k0b = (kt + 2) * 128;
            stage64(Ab  + k0b, 1920, nbuf,         wv, lane);
            stage32(B1b + k0b, 1920, nbuf + 8192,  tid, wv);
            stage32(B2b + k0b, 1920, nbuf + 12288, tid, wv);
            asm volatile("s_waitcnt vmcnt(8)" ::: "memory");
        } else if (kt == 13) {
            asm volatile("s_waitcnt vmcnt(4)" ::: "memory");
        } else {
            asm volatile("s_waitcnt vmcnt(0)" ::: "memory");
        }
        __builtin_amdgcn_s_barrier();
        __builtin_amdgcn_sched_barrier(0);
        char* As = lds + (kt % 3) * KQ_BUF;
        char* B1s = As + 8192;
        char* B2s = As + 12288;
#pragma unroll
        for (int h = 0; h < 2; h++) {
            bf16x8 a0 = ldfrag(As,  wm + lr,      h * 4 + lq);
            bf16x8 a1 = ldfrag(As,  wm + 16 + lr, h * 4 + lq);
            bf16x8 b1 = ldfrag(B1s, wn + lr,      h * 4 + lq);
            bf16x8 b2 = ldfrag(B2s, wn + lr,      h * 4 + lq);
            aK[0] = MFMA_16x16x32_BF16(a0, b1, aK[0], 0, 0, 0);
            aK[1] = MFMA_16x16x32_BF16(a1, b1, aK[1], 0, 0, 0);
            aQ[0] = MFMA_16x16x32_BF16(a0, b2, aQ[0], 0, 0, 0);
            aQ[1] = MFMA_16x16x32_BF16(a1, b2, aQ[1], 0, 0, 0);
        }
        __builtin_amdgcn_sched_barrier(0);
        __builtin_amdgcn_s_barrier();
    }
    const float c2 = 2.885390081777927f;  // 2*log2(e)
#pragma unroll
    for (int mi = 0; mi < 2; mi++)
#pragma unroll
        for (int reg = 0; reg < 4; reg++) {
            int m = m0 + wm + mi * 16 + lq * 4 + reg;
            int n = n0 + wn + lr;
            EK[(size_t)m * KD + n] = exp2f(fminf(fmaxf(aK[mi][reg] * c2, -80.f), 80.f));
            EQ[(size_t)m * KD + n] = exp2f(fminf(fmaxf(aQ[mi][reg] * c2, -80.f), 80.f));
        }
}

// =============== attention logits + softmax -> S (bf16 probs) ==================
// logit = -2*sum_d w_d*rcp(EK_jd*EQ_id+1); block (b, 3 i-rows), 512 thr,
// grid 512 = exactly 2 blocks/CU. EK reg prefetch; 3 accs per load (more ILP);
// partials pre-reduced 64->16 lanes via 2 shfl_xor, then batched LDS reduce.
__global__ __launch_bounds__(512) void attn_kernel(
    const float* __restrict__ EK, const float* __restrict__ EQ,
    const float* __restrict__ w_a, __hip_bfloat16* __restrict__ S) {
    __shared__ __align__(16) float part[8][36][17];  // [wave][jk*3+row][lane16]
    __shared__ float logit_s[3][96];
    int bid = blockIdx.x;
    int b = bid & 15, i0 = (bid >> 4) * 3;
    int tid = threadIdx.x;
    int lane = tid & 63, wv = tid >> 6;
    bool act = lane < 60;

    int col[4];
    float4 w4[4], eq[4][3];
#pragma unroll
    for (int s = 0; s < 4; s++) {
        col[s] = act ? s * 240 + lane * 4 : 0;
        if (act) w4[s] = *(const float4*)(w_a + s * 240 + lane * 4);
        else     w4[s] = float4{0.f, 0.f, 0.f, 0.f};
#pragma unroll
        for (int i = 0; i < 3; i++)
            eq[s][i] = *(const float4*)(EQ + ((size_t)b * 96 + i0 + i) * KD + col[s]);
    }

    const float* ekbase = EK + (size_t)b * 96 * KD;
    float4 ekc[4];
#pragma unroll
    for (int s = 0; s < 4; s++)
        ekc[s] = *(const float4*)(ekbase + (size_t)wv * KD + col[s]);

    for (int jk = 0; jk < 12; jk++) {
        float4 ekn[4];
        if (jk < 11) {
            const float* nrow = ekbase + (size_t)(wv + (jk + 1) * 8) * KD;
#pragma unroll
            for (int s = 0; s < 4; s++) ekn[s] = *(const float4*)(nrow + col[s]);
        }
        float a0 = 0.f, a1 = 0.f, a2 = 0.f;
#pragma unroll
        for (int s = 0; s < 4; s++) {
#pragma unroll
            for (int c = 0; c < 4; c++) {
                float ekv = ((const float*)&ekc[s])[c];
                float wc  = ((const float*)&w4[s])[c];
                float r0 = __builtin_amdgcn_rcpf(__builtin_fmaf(ekv, ((const float*)&eq[s][0])[c], 1.f));
                float r1 = __builtin_amdgcn_rcpf(__builtin_fmaf(ekv, ((const float*)&eq[s][1])[c], 1.f));
                float r2 = __builtin_amdgcn_rcpf(__builtin_fmaf(ekv, ((const float*)&eq[s][2])[c], 1.f));
                a0 = __builtin_fmaf(wc, r0, a0);
                a1 = __builtin_fmaf(wc, r1, a1);
                a2 = __builtin_fmaf(wc, r2, a2);
            }
        }
        // pre-reduce 64 -> 16 lanes (2 butterfly steps), then LDS
        a0 += __shfl_xor(a0, 32); a0 += __shfl_xor(a0, 16);
        a1 += __shfl_xor(a1, 32); a1 += __shfl_xor(a1, 16);
        a2 += __shfl_xor(a2, 32); a2 += __shfl_xor(a2, 16);
        if (lane < 16) {
            part[wv][jk * 3 + 0][lane] = a0;
            part[wv][jk * 3 + 1][lane] = a1;
            part[wv][jk * 3 + 2][lane] = a2;
        }
#pragma unroll
        for (int s = 0; s < 4; s++) ekc[s] = ekn[s];
    }
    __syncthreads();

    // batched reduction: 288 rows x 16 floats
    if (tid < 288) {
        int w2 = tid / 36, r = tid % 36;
        const float* p = &part[w2][r][0];
        float s = 0.f;
#pragma unroll
        for (int i = 0; i < 16; i++) s += p[i];
        int jk = r / 3, row = r % 3;
        logit_s[row][w2 + jk * 8] = -2.f * s;
    }
    __syncthreads();

    if (wv < 3) {
        float x0 = logit_s[wv][lane];
        float x1 = (lane < 32) ? logit_s[wv][lane + 64] : -1e30f;
        float mx = fmaxf(x0, x1);
#pragma unroll
        for (int off = 32; off; off >>= 1) mx = fmaxf(mx, __shfl_xor(mx, off));
        float e0 = __expf(x0 - mx);
        float e1 = (lane < 32) ? __expf(x1 - mx) : 0.f;
        float sm = e0 + e1;
#pragma unroll
        for (int off = 32; off; off >>= 1) sm += __shfl_xor(sm, off);
        float inv = __fdividef(1.f, sm);
        logit_s[wv][lane] = e0 * inv;
        if (lane < 32) logit_s[wv][lane + 64] = e1 * inv;
    }
    __syncthreads();

    if (tid < 288) {
        int i = tid / 96, j = tid % 96;
        S[((size_t)b * 96 + i0 + i) * 96 + j] = __float2bfloat16(logit_s[i][j]);
    }
}

// =============== fused: h_aT tile MFMA -> decay -> h_rT + dense-interp =========
__global__ __launch_bounds__(64) void hatdecay_kernel(
    const __hip_bfloat16* __restrict__ heT, const __hip_bfloat16* __restrict__ S,
    const float* __restrict__ MT, const float* __restrict__ DFT,
    const float* __restrict__ W_td, const float* __restrict__ b_td,
    float* __restrict__ h_rT, float* __restrict__ v) {
    __shared__ float ha_s[16][97];
    __shared__ float hr_s[16][97];
    int b = blockIdx.x / 60;
    int d0 = (blockIdx.x % 60) * 16;
    int lane = threadIdx.x, lq = lane >> 4, lr = lane & 15;

    const char* Ab = (const char*)heT + ((size_t)b * 960 + d0) * 192;
    const char* Bb = (const char*)S + (size_t)b * 96 * 192;
    f32x4 acc[6] = {};
#pragma unroll
    for (int kt = 0; kt < 3; kt++) {
        bf16x8 a = *(const bf16x8*)(Ab + (size_t)lr * 192 + kt * 64 + lq * 16);
#pragma unroll
        for (int ni = 0; ni < 6; ni++) {
            bf16x8 bf = *(const bf16x8*)(Bb + (size_t)(ni * 16 + lr) * 192 + kt * 64 + lq * 16);
            acc[ni] = MFMA_16x16x32_BF16(a, bf, acc[ni], 0, 0, 0);
        }
    }
#pragma unroll
    for (int ni = 0; ni < 6; ni++)
#pragma unroll
        for (int reg = 0; reg < 4; reg++)
            ha_s[lq * 4 + reg][ni * 16 + lr] = acc[ni][reg];
    __syncthreads();

    int d_base = d0 % 96;
#pragma unroll 4
    for (int rr = 0; rr < 16; rr++) {
        int kd = d0 + rr;
        int dd = d_base + rr;
        float wtd = W_td[kd], btd = b_td[kd];
        const float* mrow  = MT  + ((size_t)b * 96 + dd) * 96;
        const float* dfrow = DFT + ((size_t)b * 96 + dd) * 96;
        float* hrow = h_rT + ((size_t)b * 960 + kd) * 96;
#pragma unroll
        for (int half = 0; half < 2; half++) {
            int t = half * 64 + lane;
            if (t < 96) {
                float ha = ha_s[rr][t];
                float m  = mrow[t];
                float df = dfrow[t];
                float g  = __expf(-fmaxf(__builtin_fmaf(df, wtd, btd), 0.f));
                int tsrc = t - (int)df + 1;
                float hf = ha_s[rr][tsrc];
                float hr = m * ha + (1.f - m) * (g * hf + (1.f - g) * ha);
                hrow[t] = hr;
                hr_s[rr][t] = hr;
            }
        }
    }
    __syncthreads();

    if (lane < 48) {
        int rr = lane & 15, f = lane >> 4;
        float fp1 = 1.f + (float)f;
        float a = 0.f;
        for (int t = 0; t < 96; t++) {
            float p  = (float)(3 * (t + 1)) * (1.f / 96.f);
            float wf = 1.f - fabsf(p - fp1) * (1.f / 3.f);
            a = __builtin_fmaf(wf * wf, hr_s[rr][t], a);
        }
        v[(size_t)b * 2880 + (d0 + rr) * 3 + f] = a;
    }
}

// =============== imputation (LDS-tiled, coalesced both sides) + final FC =======
__global__ __launch_bounds__(256) void imputfc_kernel(
    const float* __restrict__ h_rT, const float* __restrict__ Wdiag,
    const float* __restrict__ b_imp, float* __restrict__ imput,
    const float* __restrict__ v, const float* __restrict__ W_fc,
    const float* __restrict__ b_fc, float* __restrict__ out) {
    int bid = blockIdx.x;
    int tid = threadIdx.x;
    if (bid < NB * 12) {
        __shared__ float tile[960 * 9];   // [kd][t-pad9], conflict-free
        int b = bid / 12, t0 = (bid % 12) * 8;
        const float* src = h_rT + (size_t)b * 960 * 96 + t0;
        for (int i = tid; i < 960 * 8; i += 256) {
            int row = i >> 3, c = i & 7;
            tile[row * 9 + c] = src[(size_t)row * 96 + c];
        }
        __syncthreads();
        if (tid < 192) {
            int tp = tid / 96, d = tid % 96;
#pragma unroll
            for (int tt = 0; tt < 4; tt++) {
                int t = tp * 4 + tt;
                float s = b_imp[d];
#pragma unroll
                for (int k = 0; k < 10; k++)
                    s = __builtin_fmaf(Wdiag[k * 96 + d], tile[(k * 96 + d) * 9 + t], s);
                imput[((size_t)b * 96 + t0 + t) * 96 + d] = s;
            }
        }
        return;
    }
    int idx = bid - NB * 12;
    if (tid >= 64) return;
    int b = idx / 10, o = idx % 10;
    const float* vp = v + (size_t)b * 2880;
    const float* wp = W_fc + (size_t)o * 2880;
    float s = 0.f;
    for (int j = tid; j < 2880; j += 64) s += vp[j] * wp[j];
#pragma unroll
    for (int off = 32; off; off >>= 1) s += __shfl_down(s, off);
    if (tid == 0) out[b * 10 + o] = s + b_fc[o];
}

extern "C" void kernel_launch(void* const* d_in, const int* in_sizes, int n_in,
                              void* d_out, int out_size, void* d_ws, size_t ws_size,
                              hipStream_t stream) {
    const float* X    = (const float*)d_in[0];
    const float* M    = (const float*)d_in[1];
    const float* DF   = (const float*)d_in[2];
    const float* W_e  = (const float*)d_in[3];
    const float* b_e  = (const float*)d_in[4];
    const float* pos  = (const float*)d_in[5];
    const float* W_a  = (const float*)d_in[6];
    const float* V_a  = (const float*)d_in[7];
    const float* w_a  = (const float*)d_in[8];
    const float* W_td = (const float*)d_in[9];
    const float* b_td = (const float*)d_in[10];
    const float* W_imp= (const float*)d_in[11];
    const float* b_imp= (const float*)d_in[12];
    const float* W_fc = (const float*)d_in[13];
    const float* b_fc = (const float*)d_in[14];

    float* out   = (float*)d_out;         // (16,10)
    float* imput = (float*)d_out + 160;   // (16,96,96)

    char* w = (char*)d_ws;
    __hip_bfloat16* Wab  = (__hip_bfloat16*)(w);             // 1,843,200
    __hip_bfloat16* Vab  = (__hip_bfloat16*)(w + 1843200);   // 1,843,200
    __hip_bfloat16* heb  = (__hip_bfloat16*)(w + 3686400);   // 2,949,120
    __hip_bfloat16* heT  = (__hip_bfloat16*)(w + 6635520);   // 2,949,120
    __hip_bfloat16* Sp   = (__hip_bfloat16*)(w + 9584640);   //   294,912
    float* MT   = (float*)(w + 9879552);                     //   589,824
    float* DFT  = (float*)(w + 10469376);                    //   589,824
    float* EKf  = (float*)(w + 11059200);                    // 5,898,240
    float* EQf  = (float*)(w + 16957440);                    // 5,898,240
    float* h_rT = EKf;   // EKf dead after attn
    float* vv   = (float*)(w + 22855680);                    //   184,320
    float* Wdiag= (float*)(w + 23040000);                    //     3,840

    // 720 embed-MFMA blocks + 8356 elementwise blocks
    embedprep_kernel<<<9076, 256, 0, stream>>>(X, M, DF, W_e, W_a, V_a, W_imp,
                                               b_e, pos, heb, heT, Wab, Vab,
                                               MT, DFT, Wdiag);
    kq_mfma<<<dim3(30, 24), 256, 0, stream>>>(heb, Wab, Vab, EKf, EQf);
    attn_kernel<<<NB * 32, 512, 0, stream>>>(EKf, EQf, w_a, Sp);
    hatdecay_kernel<<<NB * 60, 64, 0, stream>>>(heT, Sp, MT, DFT, W_td, b_td, h_rT, vv);
    imputfc_kernel<<<NB * 12 + 160, 256, 0, stream>>>(h_rT, Wdiag, b_imp, imput,
                                                      vv, W_fc, b_fc, out);
}

// Round 20
// 84.225 us; speedup vs baseline: 1.0194x; 1.0194x over previous
//
#include <hip/hip_runtime.h>
#include <hip/hip_bf16.h>

#define KD 960
#define BT 1536   // 16*96
#define NB 16

typedef __attribute__((ext_vector_type(8))) short bf16x8;
typedef __attribute__((ext_vector_type(4))) float f32x4;

#define MFMA_16x16x32_BF16 __builtin_amdgcn_mfma_f32_16x16x32_bf16

// pack 8 f32 -> 8 bf16 (16B) and store to LDS
__device__ __forceinline__ void pack8(float4 a, float4 b, void* dst) {
    union { short s[8]; bf16x8 v; } u;
#pragma unroll
    for (int i = 0; i < 4; i++) {
        __hip_bfloat16 h0 = __float2bfloat16(((const float*)&a)[i]);
        __hip_bfloat16 h1 = __float2bfloat16(((const float*)&b)[i]);
        u.s[i]     = *(short*)&h0;
        u.s[i + 4] = *(short*)&h1;
    }
    *(bf16x8*)dst = u.v;
}

__device__ __forceinline__ bf16x8 ldfrag(const char* lds, int row, int slot) {
    int ss = slot ^ (row & 7);
    return *(const bf16x8*)(lds + row * 128 + ss * 16);
}

// gload_lds staging: 64 rows x 64 bf16 (XOR-swizzled source), 4-wave form
__device__ __forceinline__ void stage64(const char* gRow0, int ldbytes,
                                        char* ldsTile, int wv, int lane) {
#pragma unroll
    for (int rd = 0; rd < 2; rd++) {
        int c  = rd * 256 + wv * 64 + lane;
        int r  = c >> 3;
        int sl = c & 7;
        int ss = sl ^ (r & 7);
        const char* g = gRow0 + (size_t)r * ldbytes + ss * 16;
        __builtin_amdgcn_global_load_lds((const void*)g,
            (void*)(ldsTile + rd * 4096 + wv * 1024), 16, 0, 0);
    }
}
// 32 rows x 64 bf16 (4KB), one 16B load per thread (256 thr)
__device__ __forceinline__ void stage32(const char* gRow0, int ldbytes,
                                        char* ldsTile, int tid, int wv) {
    int r  = tid >> 3;
    int sl = tid & 7;
    int ss = sl ^ (r & 7);
    const char* g = gRow0 + (size_t)r * ldbytes + ss * 16;
    __builtin_amdgcn_global_load_lds((const void*)g,
        (void*)(ldsTile + wv * 1024), 16, 0, 0);
}

// =============== embed MFMA (reg-staged concat/W_e) + elementwise prep ========
__global__ __launch_bounds__(256) void embedprep_kernel(
    const float* __restrict__ X, const float* __restrict__ M,
    const float* __restrict__ DF, const float* __restrict__ We,
    const float* __restrict__ Wa, const float* __restrict__ Va,
    const float* __restrict__ W_imp,
    const float* __restrict__ b_e, const float* __restrict__ pos,
    __hip_bfloat16* __restrict__ heb, __hip_bfloat16* __restrict__ heT,
    __hip_bfloat16* __restrict__ Wab, __hip_bfloat16* __restrict__ Vab,
    float* __restrict__ MT, float* __restrict__ DFT,
    float* __restrict__ Wdiag) {
    int bid = blockIdx.x;
    if (bid < 720) {
        __shared__ __align__(16) char lds[12288];
        char* As = lds; char* Bs = lds + 4096;
        int tid = threadIdx.x, lane = tid & 63, wv = tid >> 6;
        int lq = lane >> 4, lr = lane & 15;
        int m0 = (bid / 15) * 32, n0 = (bid % 15) * 64;
        int wm = (wv >> 1) * 16, wn = (wv & 1) * 32;
        int r8 = tid >> 3, sl = tid & 7;
        f32x4 acc[2] = {};
        for (int kt = 0; kt < 5; kt++) {
            int c = kt * 64 + sl * 8;
            {
                int m = m0 + r8;
                float4 f0 = {0.f,0.f,0.f,0.f}, f1 = {0.f,0.f,0.f,0.f};
                if (c < 96) {
                    const float* s = X + (size_t)m * 96 + c;
                    f0 = *(const float4*)s; f1 = *(const float4*)(s + 4);
                } else if (c < 192) {
                    const float* s = M + (size_t)m * 96 + (c - 96);
                    f0 = *(const float4*)s; f1 = *(const float4*)(s + 4);
                } else if (c < 288) {
                    const float* s = DF + (size_t)m * 96 + (c - 192);
                    f0 = *(const float4*)s; f1 = *(const float4*)(s + 4);
                }
                pack8(f0, f1, As + r8 * 128 + ((sl ^ (r8 & 7)) * 16));
            }
#pragma unroll
            for (int h = 0; h < 2; h++) {
                int row = h * 32 + r8;
                int n = n0 + row;
                float4 f0 = {0.f,0.f,0.f,0.f}, f1 = {0.f,0.f,0.f,0.f};
                if (c < 288) {
                    const float* s = We + (size_t)n * 288 + c;
                    f0 = *(const float4*)s; f1 = *(const float4*)(s + 4);
                }
                pack8(f0, f1, Bs + row * 128 + ((sl ^ (row & 7)) * 16));
            }
            __syncthreads();
#pragma unroll
            for (int h = 0; h < 2; h++) {
                bf16x8 a  = ldfrag(As, wm + lr, h * 4 + lq);
                bf16x8 b0 = ldfrag(Bs, wn + lr,      h * 4 + lq);
                bf16x8 b1 = ldfrag(Bs, wn + 16 + lr, h * 4 + lq);
                acc[0] = MFMA_16x16x32_BF16(a, b0, acc[0], 0, 0, 0);
                acc[1] = MFMA_16x16x32_BF16(a, b1, acc[1], 0, 0, 0);
            }
            __syncthreads();
        }
        int mbase = m0 + wm + lq * 4;
        int b = mbase / 96, t0 = mbase % 96;
#pragma unroll
        for (int ni = 0; ni < 2; ni++) {
            int n = n0 + wn + ni * 16 + lr;
            float bn = b_e[n];
            ushort4 pk;
#pragma unroll
            for (int reg = 0; reg < 4; reg++) {
                int t = t0 + reg;
                float x = acc[ni][reg] + bn + pos[t * KD + n];
                x = x > 0.f ? x : (__expf(x) - 1.f);
                __hip_bfloat16 hv = __float2bfloat16(x);
                heb[(size_t)(mbase + reg) * KD + n] = hv;
                ((unsigned short*)&pk)[reg] = *(unsigned short*)&hv;
            }
            *(ushort4*)((char*)heT + (((size_t)b * 960 + n) * 96 + t0) * 2) = pk;
        }
        return;
    }
    // elementwise prep
    int idx = (bid - 720) * 256 + threadIdx.x;
    if (idx < 921600) { Wab[idx] = __float2bfloat16(Wa[idx]); return; }
    idx -= 921600;
    if (idx < 921600) { Vab[idx] = __float2bfloat16(Va[idx]); return; }
    idx -= 921600;
    if (idx < 147456) {               // MT[b][d][t] = M[b][t][d]
        int b = idx / 9216, r = idx % 9216, d = r / 96, t = r % 96;
        MT[idx] = M[(b * 96 + t) * 96 + d];
        return;
    }
    idx -= 147456;
    if (idx < 147456) {
        int b = idx / 9216, r = idx % 9216, d = r / 96, t = r % 96;
        DFT[idx] = DF[(b * 96 + t) * 96 + d];
        return;
    }
    idx -= 147456;
    if (idx < 960) {                  // diagonal of W_imp, kd-major
        int k = idx / 96, d = idx % 96;
        Wdiag[idx] = W_imp[d * KD + k * 96 + d];
    }
}

// =============== fused key/qry GEMM 64x32; 3-buffer 2-deep pipeline ============
#define KQ_BUF 16384   // A 8KB + B1 4KB + B2 4KB
__global__ __launch_bounds__(256) void kq_mfma(
    const __hip_bfloat16* __restrict__ A, const __hip_bfloat16* __restrict__ B1,
    const __hip_bfloat16* __restrict__ B2,
    float* __restrict__ EK, float* __restrict__ EQ) {
    __shared__ __align__(16) char lds[3 * KQ_BUF];
    int tid = threadIdx.x, lane = tid & 63, wv = tid >> 6;
    int lq = lane >> 4, lr = lane & 15;
    int m0 = blockIdx.y * 64, n0 = blockIdx.x * 32;
    int wm = (wv >> 1) * 32, wn = (wv & 1) * 16;
    const char* Ab  = (const char*)A  + (size_t)m0 * 1920;
    const char* B1b = (const char*)B1 + (size_t)n0 * 1920;
    const char* B2b = (const char*)B2 + (size_t)n0 * 1920;
    f32x4 aK[2] = {}, aQ[2] = {};

#pragma unroll
    for (int p = 0; p < 2; p++) {
        char* buf = lds + p * KQ_BUF;
        int k0b = p * 128;
        stage64(Ab  + k0b, 1920, buf,         wv, lane);
        stage32(B1b + k0b, 1920, buf + 8192,  tid, wv);
        stage32(B2b + k0b, 1920, buf + 12288, tid, wv);
    }
    for (int kt = 0; kt < 15; kt++) {
        if (kt < 13) {
            char* nbuf = lds + ((kt + 2) % 3) * KQ_BUF;
            int k0b = (kt + 2) * 128;
            stage64(Ab  + k0b, 1920, nbuf,         wv, lane);
            stage32(B1b + k0b, 1920, nbuf + 8192,  tid, wv);
            stage32(B2b + k0b, 1920, nbuf + 12288, tid, wv);
            asm volatile("s_waitcnt vmcnt(8)" ::: "memory");
        } else if (kt == 13) {
            asm volatile("s_waitcnt vmcnt(4)" ::: "memory");
        } else {
            asm volatile("s_waitcnt vmcnt(0)" ::: "memory");
        }
        __builtin_amdgcn_s_barrier();
        __builtin_amdgcn_sched_barrier(0);
        char* As = lds + (kt % 3) * KQ_BUF;
        char* B1s = As + 8192;
        char* B2s = As + 12288;
#pragma unroll
        for (int h = 0; h < 2; h++) {
            bf16x8 a0 = ldfrag(As,  wm + lr,      h * 4 + lq);
            bf16x8 a1 = ldfrag(As,  wm + 16 + lr, h * 4 + lq);
            bf16x8 b1 = ldfrag(B1s, wn + lr,      h * 4 + lq);
            bf16x8 b2 = ldfrag(B2s, wn + lr,      h * 4 + lq);
            aK[0] = MFMA_16x16x32_BF16(a0, b1, aK[0], 0, 0, 0);
            aK[1] = MFMA_16x16x32_BF16(a1, b1, aK[1], 0, 0, 0);
            aQ[0] = MFMA_16x16x32_BF16(a0, b2, aQ[0], 0, 0, 0);
            aQ[1] = MFMA_16x16x32_BF16(a1, b2, aQ[1], 0, 0, 0);
        }
        __builtin_amdgcn_sched_barrier(0);
        __builtin_amdgcn_s_barrier();
    }
    const float c2 = 2.885390081777927f;  // 2*log2(e)
#pragma unroll
    for (int mi = 0; mi < 2; mi++)
#pragma unroll
        for (int reg = 0; reg < 4; reg++) {
            int m = m0 + wm + mi * 16 + lq * 4 + reg;
            int n = n0 + wn + lr;
            EK[(size_t)m * KD + n] = exp2f(fminf(fmaxf(aK[mi][reg] * c2, -80.f), 80.f));
            EQ[(size_t)m * KD + n] = exp2f(fminf(fmaxf(aQ[mi][reg] * c2, -80.f), 80.f));
        }
}

// =============== attention logits + softmax -> S (bf16 probs) ==================
// logit = -2*sum_d w_d*rcp(EK_jd*EQ_id+1); block (b, 2 i-rows), 512 thr, grid 768.
// d-as-lane float4 slices; EK register double-buffer prefetch; batched reduction.
__global__ __launch_bounds__(512) void attn_kernel(
    const float* __restrict__ EK, const float* __restrict__ EQ,
    const float* __restrict__ w_a, __hip_bfloat16* __restrict__ S) {
    __shared__ __align__(16) float part[8][24][68];  // [wave][jloc*2+row][lane]
    __shared__ float logit_s[2][96];
    int bid = blockIdx.x;
    int b = bid & 15, i0 = (bid >> 4) * 2;
    int tid = threadIdx.x;
    int lane = tid & 63, wv = tid >> 6;
    bool act = lane < 60;

    int col[4];
    float4 w4[4], eq[4][2];
#pragma unroll
    for (int s = 0; s < 4; s++) {
        col[s] = act ? s * 240 + lane * 4 : 0;
        if (act) w4[s] = *(const float4*)(w_a + s * 240 + lane * 4);
        else     w4[s] = float4{0.f, 0.f, 0.f, 0.f};
#pragma unroll
        for (int i = 0; i < 2; i++)
            eq[s][i] = *(const float4*)(EQ + ((size_t)b * 96 + i0 + i) * KD + col[s]);
    }

    const float* ekbase = EK + (size_t)b * 96 * KD;
    float4 ekc[4];
#pragma unroll
    for (int s = 0; s < 4; s++)
        ekc[s] = *(const float4*)(ekbase + (size_t)wv * KD + col[s]);

    for (int jk = 0; jk < 12; jk++) {
        float4 ekn[4];
        if (jk < 11) {
            const float* nrow = ekbase + (size_t)(wv + (jk + 1) * 8) * KD;
#pragma unroll
            for (int s = 0; s < 4; s++) ekn[s] = *(const float4*)(nrow + col[s]);
        }
        float a0 = 0.f, a1 = 0.f;
#pragma unroll
        for (int s = 0; s < 4; s++) {
#pragma unroll
            for (int c = 0; c < 4; c++) {
                float ekv = ((const float*)&ekc[s])[c];
                float wc  = ((const float*)&w4[s])[c];
                float r0 = __builtin_amdgcn_rcpf(__builtin_fmaf(ekv, ((const float*)&eq[s][0])[c], 1.f));
                float r1 = __builtin_amdgcn_rcpf(__builtin_fmaf(ekv, ((const float*)&eq[s][1])[c], 1.f));
                a0 = __builtin_fmaf(wc, r0, a0);
                a1 = __builtin_fmaf(wc, r1, a1);
            }
        }
        part[wv][jk * 2 + 0][lane] = a0;
        part[wv][jk * 2 + 1][lane] = a1;
#pragma unroll
        for (int s = 0; s < 4; s++) ekc[s] = ekn[s];
    }

    if (lane < 24) {
        int jloc = lane % 12, row = lane / 12;
        const float* p = &part[wv][jloc * 2 + row][0];
        float4 s4 = {0.f, 0.f, 0.f, 0.f};
#pragma unroll
        for (int i = 0; i < 16; i++) {
            float4 v = *(const float4*)(p + i * 4);
            s4.x += v.x; s4.y += v.y; s4.z += v.z; s4.w += v.w;
        }
        int j = wv + jloc * 8;
        logit_s[row][j] = -2.f * (s4.x + s4.y + s4.z + s4.w);
    }
    __syncthreads();

    if (wv < 2) {
        float x0 = logit_s[wv][lane];
        float x1 = (lane < 32) ? logit_s[wv][lane + 64] : -1e30f;
        float mx = fmaxf(x0, x1);
#pragma unroll
        for (int off = 32; off; off >>= 1) mx = fmaxf(mx, __shfl_xor(mx, off));
        float e0 = __expf(x0 - mx);
        float e1 = (lane < 32) ? __expf(x1 - mx) : 0.f;
        float sm = e0 + e1;
#pragma unroll
        for (int off = 32; off; off >>= 1) sm += __shfl_xor(sm, off);
        float inv = __fdividef(1.f, sm);
        logit_s[wv][lane] = e0 * inv;
        if (lane < 32) logit_s[wv][lane + 64] = e1 * inv;
    }
    __syncthreads();

    if (tid < 192) {
        int i = tid / 96, j = tid % 96;
        S[((size_t)b * 96 + i0 + i) * 96 + j] = __float2bfloat16(logit_s[i][j]);
    }
}

// =============== fused: h_aT tile MFMA -> decay -> h_rT + dense-interp =========
__global__ __launch_bounds__(64) void hatdecay_kernel(
    const __hip_bfloat16* __restrict__ heT, const __hip_bfloat16* __restrict__ S,
    const float* __restrict__ MT, const float* __restrict__ DFT,
    const float* __restrict__ W_td, const float* __restrict__ b_td,
    float* __restrict__ h_rT, float* __restrict__ v) {
    __shared__ float ha_s[16][97];
    __shared__ float hr_s[16][97];
    int b = blockIdx.x / 60;
    int d0 = (blockIdx.x % 60) * 16;
    int lane = threadIdx.x, lq = lane >> 4, lr = lane & 15;

    const char* Ab = (const char*)heT + ((size_t)b * 960 + d0) * 192;
    const char* Bb = (const char*)S + (size_t)b * 96 * 192;
    f32x4 acc[6] = {};
#pragma unroll
    for (int kt = 0; kt < 3; kt++) {
        bf16x8 a = *(const bf16x8*)(Ab + (size_t)lr * 192 + kt * 64 + lq * 16);
#pragma unroll
        for (int ni = 0; ni < 6; ni++) {
            bf16x8 bf = *(const bf16x8*)(Bb + (size_t)(ni * 16 + lr) * 192 + kt * 64 + lq * 16);
            acc[ni] = MFMA_16x16x32_BF16(a, bf, acc[ni], 0, 0, 0);
        }
    }
#pragma unroll
    for (int ni = 0; ni < 6; ni++)
#pragma unroll
        for (int reg = 0; reg < 4; reg++)
            ha_s[lq * 4 + reg][ni * 16 + lr] = acc[ni][reg];
    __syncthreads();

    int d_base = d0 % 96;
#pragma unroll 4
    for (int rr = 0; rr < 16; rr++) {
        int kd = d0 + rr;
        int dd = d_base + rr;
        float wtd = W_td[kd], btd = b_td[kd];
        const float* mrow  = MT  + ((size_t)b * 96 + dd) * 96;
        const float* dfrow = DFT + ((size_t)b * 96 + dd) * 96;
        float* hrow = h_rT + ((size_t)b * 960 + kd) * 96;
#pragma unroll
        for (int half = 0; half < 2; half++) {
            int t = half * 64 + lane;
            if (t < 96) {
                float ha = ha_s[rr][t];
                float m  = mrow[t];
                float df = dfrow[t];
                float g  = __expf(-fmaxf(__builtin_fmaf(df, wtd, btd), 0.f));
                int tsrc = t - (int)df + 1;
                float hf = ha_s[rr][tsrc];
                float hr = m * ha + (1.f - m) * (g * hf + (1.f - g) * ha);
                hrow[t] = hr;
                hr_s[rr][t] = hr;
            }
        }
    }
    __syncthreads();

    if (lane < 48) {
        int rr = lane & 15, f = lane >> 4;
        float fp1 = 1.f + (float)f;
        float a = 0.f;
        for (int t = 0; t < 96; t++) {
            float p  = (float)(3 * (t + 1)) * (1.f / 96.f);
            float wf = 1.f - fabsf(p - fp1) * (1.f / 3.f);
            a = __builtin_fmaf(wf * wf, hr_s[rr][t], a);
        }
        v[(size_t)b * 2880 + (d0 + rr) * 3 + f] = a;
    }
}

// =============== imputation (LDS-tiled, coalesced both sides) + final FC =======
__global__ __launch_bounds__(256) void imputfc_kernel(
    const float* __restrict__ h_rT, const float* __restrict__ Wdiag,
    const float* __restrict__ b_imp, float* __restrict__ imput,
    const float* __restrict__ v, const float* __restrict__ W_fc,
    const float* __restrict__ b_fc, float* __restrict__ out) {
    int bid = blockIdx.x;
    int tid = threadIdx.x;
    if (bid < NB * 12) {
        __shared__ float tile[960 * 9];   // [kd][t-pad9], conflict-free
        int b = bid / 12, t0 = (bid % 12) * 8;
        const float* src = h_rT + (size_t)b * 960 * 96 + t0;
        for (int i = tid; i < 960 * 8; i += 256) {
            int row = i >> 3, c = i & 7;
            tile[row * 9 + c] = src[(size_t)row * 96 + c];
        }
        __syncthreads();
        if (tid < 192) {
            int tp = tid / 96, d = tid % 96;
#pragma unroll
            for (int tt = 0; tt < 4; tt++) {
                int t = tp * 4 + tt;
                float s = b_imp[d];
#pragma unroll
                for (int k = 0; k < 10; k++)
                    s = __builtin_fmaf(Wdiag[k * 96 + d], tile[(k * 96 + d) * 9 + t], s);
                imput[((size_t)b * 96 + t0 + t) * 96 + d] = s;
            }
        }
        return;
    }
    int idx = bid - NB * 12;
    if (tid >= 64) return;
    int b = idx / 10, o = idx % 10;
    const float* vp = v + (size_t)b * 2880;
    const float* wp = W_fc + (size_t)o * 2880;
    float s = 0.f;
    for (int j = tid; j < 2880; j += 64) s += vp[j] * wp[j];
#pragma unroll
    for (int off = 32; off; off >>= 1) s += __shfl_down(s, off);
    if (tid == 0) out[b * 10 + o] = s + b_fc[o];
}

extern "C" void kernel_launch(void* const* d_in, const int* in_sizes, int n_in,
                              void* d_out, int out_size, void* d_ws, size_t ws_size,
                              hipStream_t stream) {
    const float* X    = (const float*)d_in[0];
    const float* M    = (const float*)d_in[1];
    const float* DF   = (const float*)d_in[2];
    const float* W_e  = (const float*)d_in[3];
    const float* b_e  = (const float*)d_in[4];
    const float* pos  = (const float*)d_in[5];
    const float* W_a  = (const float*)d_in[6];
    const float* V_a  = (const float*)d_in[7];
    const float* w_a  = (const float*)d_in[8];
    const float* W_td = (const float*)d_in[9];
    const float* b_td = (const float*)d_in[10];
    const float* W_imp= (const float*)d_in[11];
    const float* b_imp= (const float*)d_in[12];
    const float* W_fc = (const float*)d_in[13];
    const float* b_fc = (const float*)d_in[14];

    float* out   = (float*)d_out;         // (16,10)
    float* imput = (float*)d_out + 160;   // (16,96,96)

    char* w = (char*)d_ws;
    __hip_bfloat16* Wab  = (__hip_bfloat16*)(w);             // 1,843,200
    __hip_bfloat16* Vab  = (__hip_bfloat16*)(w + 1843200);   // 1,843,200
    __hip_bfloat16* heb  = (__hip_bfloat16*)(w + 3686400);   // 2,949,120
    __hip_bfloat16* heT  = (__hip_bfloat16*)(w + 6635520);   // 2,949,120
    __hip_bfloat16* Sp   = (__hip_bfloat16*)(w + 9584640);   //   294,912
    float* MT   = (float*)(w + 9879552);                     //   589,824
    float* DFT  = (float*)(w + 10469376);                    //   589,824
    float* EKf  = (float*)(w + 11059200);                    // 5,898,240
    float* EQf  = (float*)(w + 16957440);                    // 5,898,240
    float* h_rT = EKf;   // EKf dead after attn
    float* vv   = (float*)(w + 22855680);                    //   184,320
    float* Wdiag= (float*)(w + 23040000);                    //     3,840

    // 720 embed-MFMA blocks + 8356 elementwise blocks
    embedprep_kernel<<<9076, 256, 0, stream>>>(X, M, DF, W_e, W_a, V_a, W_imp,
                                               b_e, pos, heb, heT, Wab, Vab,
                                               MT, DFT, Wdiag);
    kq_mfma<<<dim3(30, 24), 256, 0, stream>>>(heb, Wab, Vab, EKf, EQf);
    attn_kernel<<<NB * 48, 512, 0, stream>>>(EKf, EQf, w_a, Sp);
    hatdecay_kernel<<<NB * 60, 64, 0, stream>>>(heT, Sp, MT, DFT, W_td, b_td, h_rT, vv);
    imputfc_kernel<<<NB * 12 + 160, 256, 0, stream>>>(h_rT, Wdiag, b_imp, imput,
                                                      vv, W_fc, b_fc, out);
}